// Round 4
// baseline (559.579 us; speedup 1.0000x reference)
//
#include <hip/hip_runtime.h>
#include <hip/hip_bf16.h>
#include <cstdint>

#define DEVI __device__ __forceinline__

using bf16x8 = __attribute__((ext_vector_type(8))) short;
using f32x4  = __attribute__((ext_vector_type(4))) float;

DEVI short f2b(float f) {
  __hip_bfloat16 h = __float2bfloat16(f);
  return *reinterpret_cast<short*>(&h);
}
DEVI float b2f(short s) {
  __hip_bfloat16 h = *reinterpret_cast<__hip_bfloat16*>(&s);
  return __bfloat162float(h);
}
DEVI uint32_t pk2(float a, float b) {
  return (uint32_t)(uint16_t)f2b(a) | ((uint32_t)(uint16_t)f2b(b) << 16);
}

DEVI f32x4 mfma16(bf16x8 a, bf16x8 b, f32x4 c) {
  return __builtin_amdgcn_mfma_f32_16x16x32_bf16(a, b, c, 0, 0, 0);
}

DEVI void gload_lds16(const void* g, void* l) {
  __builtin_amdgcn_global_load_lds(
      (const __attribute__((address_space(1))) void*)g,
      (__attribute__((address_space(3))) void*)l, 16, 0, 0);
}

DEVI float gelu_f(float x) {
  float u = 1.5957691216057308f * (x + 0.044715f * x * x * x); // 2z
  float e = __expf(u);
  float t = 1.f - 2.f / (e + 1.f); // tanh(z)
  return 0.5f * x * (1.f + t);
}

// ---------------- weight transpose + fp32->bf16 convert ----------------
__global__ void k_wt(const float* __restrict__ in, short* __restrict__ out,
                     int R, int Cc) {
  __shared__ float tile[32][33];
  int c0 = blockIdx.x * 32;
  int r0 = blockIdx.y * 32;
  int tx = threadIdx.x, ty = threadIdx.y;
  for (int i = ty; i < 32; i += 8) {
    int r = r0 + i, c = c0 + tx;
    tile[i][tx] = (r < R && c < Cc) ? in[(size_t)r * Cc + c] : 0.f;
  }
  __syncthreads();
  for (int i = ty; i < 32; i += 8) {
    int orow = c0 + i;
    int ocol = r0 + tx;
    if (orow < Cc && ocol < R) out[(size_t)orow * R + ocol] = f2b(tile[tx][i]);
  }
}

// ---------------- layernorm: fp32 in -> bf16 out (C=1024) ----------------
__global__ void k_layernorm(const float* __restrict__ x, const float* __restrict__ g,
                            const float* __restrict__ bta, short* __restrict__ out) {
  const int C = 1024;
  int row = blockIdx.x;
  const float* xr = x + (size_t)row * C;
  f32x4 v = *(const f32x4*)(xr + threadIdx.x * 4);
  float s = v[0] + v[1] + v[2] + v[3];
  float s2 = v[0]*v[0] + v[1]*v[1] + v[2]*v[2] + v[3]*v[3];
#pragma unroll
  for (int m = 1; m < 64; m <<= 1) { s += __shfl_xor(s, m); s2 += __shfl_xor(s2, m); }
  __shared__ float red[8];
  int w = threadIdx.x >> 6;
  if ((threadIdx.x & 63) == 0) { red[w] = s; red[4 + w] = s2; }
  __syncthreads();
  s = red[0] + red[1] + red[2] + red[3];
  s2 = red[4] + red[5] + red[6] + red[7];
  float mu = s * (1.f / 1024.f);
  float rstd = rsqrtf(s2 * (1.f / 1024.f) - mu * mu + 1e-5f);
#pragma unroll
  for (int j = 0; j < 4; ++j) {
    int c = threadIdx.x * 4 + j;
    out[(size_t)row * C + c] = f2b((v[j] - mu) * rstd * g[c] + bta[c]);
  }
}

// ---------------- V transpose: qkv bf16 [4096][3072] -> vT [32][64][2048] ----------------
__global__ void k_vtrans(const short* __restrict__ qkv, short* __restrict__ vT) {
  __shared__ short tile[32][72];
  int b = blockIdx.z, h = blockIdx.y;
  int t0 = blockIdx.x * 32;
  int tx = threadIdx.x;
  int ty = threadIdx.y;
  const size_t inbase = ((size_t)(b * 2048 + t0)) * 3072 + 2048 + h * 64;
  for (int i = ty; i < 32; i += 8) {
    tile[i][tx]      = qkv[inbase + (size_t)i * 3072 + tx];
    tile[i][tx + 32] = qkv[inbase + (size_t)i * 3072 + tx + 32];
  }
  __syncthreads();
  const size_t outbase = ((size_t)(b * 16 + h) * 64) * 2048 + t0;
  for (int d = ty; d < 64; d += 8)
    vT[outbase + (size_t)d * 2048 + tx] = tile[tx][d];
}

// ---------------- GEMM ----------------
template <int BM, int BN, int WGM, int WGN, int ACT, bool RESID, bool OUTF, bool OUTB>
__global__ __launch_bounds__(256, 2) void k_gemm(
    const short* __restrict__ A, const short* __restrict__ BT,
    const float* __restrict__ bias, const float* __restrict__ resid,
    float* __restrict__ outf, short* __restrict__ outb,
    int M, int N, int K) {
  static_assert(WGM * WGN == 4, "4 waves");
  constexpr int TM = BM / WGM, TN = BN / WGN;
  constexpr int FM = TM / 16, FN = TN / 16;
  __shared__ short As[BM * 32];
  __shared__ short Bs[BN * 32];
  const int tid = threadIdx.x;
  const int wid = tid >> 6, l = tid & 63, lr = l & 15, lg = l >> 4;
  const int wm = wid / WGN, wn = wid % WGN;
  const int rowA0 = blockIdx.x * BM;
  const int colB0 = blockIdx.y * BN;

  f32x4 acc[FM][FN];
#pragma unroll
  for (int i = 0; i < FM; ++i)
#pragma unroll
    for (int j = 0; j < FN; ++j) acc[i][j] = f32x4{0.f, 0.f, 0.f, 0.f};

  for (int k0 = 0; k0 < K; k0 += 32) {
    __syncthreads();
#pragma unroll
    for (int it = 0; it < (BM * 64) / 4096; ++it) {
      int bo = it * 4096 + tid * 16;
      int row = bo >> 6, col = (bo & 63) >> 1;
      gload_lds16(A + (size_t)(rowA0 + row) * K + k0 + col, (void*)(As + (bo >> 1)));
    }
#pragma unroll
    for (int it = 0; it < (BN * 64) / 4096; ++it) {
      int bo = it * 4096 + tid * 16;
      int row = bo >> 6, col = (bo & 63) >> 1;
      gload_lds16(BT + (size_t)(colB0 + row) * K + k0 + col, (void*)(Bs + (bo >> 1)));
    }
    __syncthreads();
    bf16x8 af[FM], bfr[FN];
#pragma unroll
    for (int i = 0; i < FM; ++i)
      af[i] = *(const bf16x8*)(As + (wm * TM + i * 16 + lr) * 32 + lg * 8);
#pragma unroll
    for (int j = 0; j < FN; ++j)
      bfr[j] = *(const bf16x8*)(Bs + (wn * TN + j * 16 + lr) * 32 + lg * 8);
#pragma unroll
    for (int i = 0; i < FM; ++i)
#pragma unroll
      for (int j = 0; j < FN; ++j)
        acc[i][j] = mfma16(af[i], bfr[j], acc[i][j]);
  }

  const int row0 = rowA0 + wm * TM + lg * 4;
  const int col0 = colB0 + wn * TN + lr;
#pragma unroll
  for (int i = 0; i < FM; ++i) {
#pragma unroll
    for (int j = 0; j < FN; ++j) {
#pragma unroll
      for (int r = 0; r < 4; ++r) {
        int row = row0 + i * 16 + r;
        int col = col0 + j * 16;
        float v = acc[i][j][r] + bias[col];
        if (ACT == 1) v = fmaxf(v, 0.f);
        if (ACT == 2) v = gelu_f(v);
        size_t idx = (size_t)row * N + col;
        if (RESID) v += resid[idx];
        if (OUTF) outf[idx] = v;
        if (OUTB) outb[idx] = f2b(v);
      }
    }
  }
}

// ---------------- flash-style causal attention (swapped QK^T) ----------------
// qkv bf16 [4096][3072]; vT bf16 [32][64][2048]; y bf16 [4096][1024]
// Wave handles 16 q rows. S^T = mfma(K, Q): lane (lr,lg) reg r holds
// S[kv = lg*4+r (+16 for tile1)][q = lr]. Softmax in exp2 domain
// (0.125*log2e folded into Q). P staged packed through per-wave LDS,
// consumed as PV B-operand; O^T accumulated (col=q, row=d).
__global__ __launch_bounds__(256, 4) void k_attn(
    const short* __restrict__ qkv, const short* __restrict__ vT,
    short* __restrict__ y) {
  constexpr int T = 2048, C3 = 3072;
  const int tid = threadIdx.x;
  const int wid = tid >> 6, l = tid & 63, lr = l & 15, lg = l >> 4;
  const int bh = blockIdx.x, b = bh >> 4, h = bh & 15;
  const int qt = (int)(gridDim.y - 1 - blockIdx.y);  // longest-first
  const int q0 = qt * 64 + wid * 16;

  __shared__ short Plds[4][16][32];  // [wave][q][kv_rel]

  // Q fragment (B-operand layout): Q[q=lr][d=lg*8+j] * 0.125*log2(e)
  const float qscale = 0.125f * 1.4426950408889634f;
  const short* qptr = qkv + (size_t)(b * T + q0 + lr) * C3 + h * 64;
  bf16x8 qr0 = *(const bf16x8*)(qptr + lg * 8);
  bf16x8 qr1 = *(const bf16x8*)(qptr + 32 + lg * 8);
  bf16x8 qf0, qf1;
#pragma unroll
  for (int j = 0; j < 8; ++j) {
    qf0[j] = f2b(b2f(qr0[j]) * qscale);
    qf1[j] = f2b(b2f(qr1[j]) * qscale);
  }

  const short* kbase = qkv + (size_t)(b * T) * C3 + 1024 + h * 64;
  const short* vtb = vT + (size_t)bh * 64 * 2048;

  f32x4 o[4];
#pragma unroll
  for (int d = 0; d < 4; ++d) o[d] = f32x4{0.f, 0.f, 0.f, 0.f};
  float m = -1e30f, lsum = 0.f;

  const int kv_full = q0 & ~31;  // tiles below this need no mask

  auto body = [&](int kv0, bool mask) {
    const short* kp = kbase + (size_t)(kv0 + lr) * C3;
    bf16x8 kf00 = *(const bf16x8*)(kp + lg * 8);
    bf16x8 kf01 = *(const bf16x8*)(kp + 32 + lg * 8);
    const short* kp1 = kp + (size_t)16 * C3;
    bf16x8 kf10 = *(const bf16x8*)(kp1 + lg * 8);
    bf16x8 kf11 = *(const bf16x8*)(kp1 + 32 + lg * 8);
    f32x4 s0 = {0.f, 0.f, 0.f, 0.f}, s1 = {0.f, 0.f, 0.f, 0.f};
    s0 = mfma16(kf00, qf0, s0);
    s0 = mfma16(kf01, qf1, s0);
    s1 = mfma16(kf10, qf0, s1);
    s1 = mfma16(kf11, qf1, s1);
    if (mask) {
      const int q = q0 + lr;
#pragma unroll
      for (int r = 0; r < 4; ++r) {
        if (kv0 + lg * 4 + r > q) s0[r] = -1e30f;
        if (kv0 + 16 + lg * 4 + r > q) s1[r] = -1e30f;
      }
    }
    float mx = fmaxf(fmaxf(fmaxf(s0[0], s0[1]), fmaxf(s0[2], s0[3])),
                     fmaxf(fmaxf(s1[0], s1[1]), fmaxf(s1[2], s1[3])));
    mx = fmaxf(mx, __shfl_xor(mx, 16));
    mx = fmaxf(mx, __shfl_xor(mx, 32));
    if (__any(mx > m + 8.f)) {  // defer-max: rescale only when needed
      float mn = fmaxf(m, mx);
      float corr = exp2f(m - mn);
      m = mn;
      lsum *= corr;
#pragma unroll
      for (int d = 0; d < 4; ++d)
#pragma unroll
        for (int r = 0; r < 4; ++r) o[d][r] *= corr;
    }
    float p0 = exp2f(s0[0] - m), p1 = exp2f(s0[1] - m);
    float p2 = exp2f(s0[2] - m), p3 = exp2f(s0[3] - m);
    float p4 = exp2f(s1[0] - m), p5 = exp2f(s1[1] - m);
    float p6 = exp2f(s1[2] - m), p7 = exp2f(s1[3] - m);
    lsum += ((p0 + p1) + (p2 + p3)) + ((p4 + p5) + (p6 + p7));
    uint2 w0, w1;
    w0.x = pk2(p0, p1); w0.y = pk2(p2, p3);
    w1.x = pk2(p4, p5); w1.y = pk2(p6, p7);
    *(uint2*)&Plds[wid][lr][lg * 4] = w0;
    *(uint2*)&Plds[wid][lr][16 + lg * 4] = w1;
    bf16x8 pf = *(const bf16x8*)&Plds[wid][lr][lg * 8];
#pragma unroll
    for (int dt = 0; dt < 4; ++dt) {
      bf16x8 vf = *(const bf16x8*)(vtb + (size_t)(dt * 16 + lr) * 2048 + kv0 + lg * 8);
      o[dt] = mfma16(vf, pf, o[dt]);
    }
  };

  for (int kv0 = 0; kv0 < kv_full; kv0 += 32) body(kv0, false);
  body(kv_full, true);  // diagonal tile

  lsum += __shfl_xor(lsum, 16);
  lsum += __shfl_xor(lsum, 32);
  float inv = 1.f / lsum;

  short* yp = y + (size_t)(b * T + q0 + lr) * 1024 + h * 64;
#pragma unroll
  for (int dt = 0; dt < 4; ++dt) {
    uint2 wv;
    wv.x = pk2(o[dt][0] * inv, o[dt][1] * inv);
    wv.y = pk2(o[dt][2] * inv, o[dt][3] * inv);
    *(uint2*)(yp + dt * 16 + lg * 4) = wv;
  }
}

extern "C" void kernel_launch(void* const* d_in, const int* in_sizes, int n_in,
                              void* d_out, int out_size, void* d_ws, size_t ws_size,
                              hipStream_t stream) {
  (void)in_sizes; (void)n_in; (void)out_size; (void)ws_size;
  const float* x0     = (const float*)d_in[0];
  const float* ln1_g  = (const float*)d_in[1];
  const float* ln1_b  = (const float*)d_in[2];
  const float* attn_w = (const float*)d_in[3];
  const float* attn_b = (const float*)d_in[4];
  const float* proj_w = (const float*)d_in[5];
  const float* proj_b = (const float*)d_in[6];
  const float* a1_dw  = (const float*)d_in[7];
  const float* a1_db  = (const float*)d_in[8];
  const float* a1_uw  = (const float*)d_in[9];
  const float* a1_ub  = (const float*)d_in[10];
  const float* ln2_g  = (const float*)d_in[11];
  const float* ln2_b  = (const float*)d_in[12];
  const float* fc_w   = (const float*)d_in[13];
  const float* fc_b   = (const float*)d_in[14];
  const float* mlp_pw = (const float*)d_in[15];
  const float* mlp_pb = (const float*)d_in[16];
  const float* a2_dw  = (const float*)d_in[17];
  const float* a2_db  = (const float*)d_in[18];
  const float* a2_uw  = (const float*)d_in[19];
  const float* a2_ub  = (const float*)d_in[20];

  char* ws = (char*)d_ws;
  size_t off = 0;
  auto alloc = [&](size_t bytes) {
    char* p = ws + off;
    off = (off + bytes + 255) & ~(size_t)255;
    return p;
  };

  short* attn_wT = (short*)alloc(3072ull * 1024 * 2);
  short* proj_wT = (short*)alloc(1024ull * 1024 * 2);
  short* fc_wT   = (short*)alloc(4096ull * 1024 * 2);
  short* mlp_pwT = (short*)alloc(1024ull * 4096 * 2);
  short* a1_dwT  = (short*)alloc(64ull * 1024 * 2);
  short* a1_uwT  = (short*)alloc(1024ull * 64 * 2);
  short* a2_dwT  = (short*)alloc(64ull * 1024 * 2);
  short* a2_uwT  = (short*)alloc(1024ull * 64 * 2);
  short* lnb     = (short*)alloc(4096ull * 1024 * 2);
  char*  big     = alloc(4096ull * 4096 * 2);
  short* qkvb    = (short*)big;
  short* vTb     = (short*)(big + 4096ull * 3072 * 2);
  short* fcb     = (short*)big;
  short* yb      = (short*)alloc(4096ull * 1024 * 2);
  float* x1f     = (float*)alloc(4096ull * 1024 * 4);
  float* x2f     = (float*)alloc(4096ull * 1024 * 4);
  short* x1b     = (short*)alloc(4096ull * 1024 * 2);
  short* hb      = (short*)alloc(4096ull * 64 * 2);

  dim3 tb(32, 8);
  k_wt<<<dim3(3072 / 32, 1024 / 32), tb, 0, stream>>>(attn_w, attn_wT, 1024, 3072);
  k_wt<<<dim3(1024 / 32, 1024 / 32), tb, 0, stream>>>(proj_w, proj_wT, 1024, 1024);
  k_wt<<<dim3(4096 / 32, 1024 / 32), tb, 0, stream>>>(fc_w, fc_wT, 1024, 4096);
  k_wt<<<dim3(1024 / 32, 4096 / 32), tb, 0, stream>>>(mlp_pw, mlp_pwT, 4096, 1024);
  k_wt<<<dim3(64 / 32, 1024 / 32), tb, 0, stream>>>(a1_dw, a1_dwT, 1024, 64);
  k_wt<<<dim3(1024 / 32, 64 / 32), tb, 0, stream>>>(a1_uw, a1_uwT, 64, 1024);
  k_wt<<<dim3(64 / 32, 1024 / 32), tb, 0, stream>>>(a2_dw, a2_dwT, 1024, 64);
  k_wt<<<dim3(1024 / 32, 64 / 32), tb, 0, stream>>>(a2_uw, a2_uwT, 64, 1024);

  k_layernorm<<<4096, 256, 0, stream>>>(x0, ln1_g, ln1_b, lnb);

  k_gemm<128, 128, 2, 2, 0, false, false, true><<<dim3(32, 24), 256, 0, stream>>>(
      lnb, attn_wT, attn_b, nullptr, nullptr, qkvb, 4096, 3072, 1024);

  k_vtrans<<<dim3(64, 16, 2), tb, 0, stream>>>(qkvb, vTb);

  k_attn<<<dim3(32, 32), 256, 0, stream>>>(qkvb, vTb, yb);

  k_gemm<128, 128, 2, 2, 0, true, true, true><<<dim3(32, 8), 256, 0, stream>>>(
      yb, proj_wT, proj_b, x0, x1f, x1b, 4096, 1024, 1024);

  k_gemm<64, 64, 2, 2, 1, false, false, true><<<dim3(64, 1), 256, 0, stream>>>(
      x1b, a1_dwT, a1_db, nullptr, nullptr, hb, 4096, 64, 1024);

  k_gemm<128, 128, 2, 2, 0, true, true, false><<<dim3(32, 8), 256, 0, stream>>>(
      hb, a1_uwT, a1_ub, x1f, x2f, nullptr, 4096, 1024, 64);

  k_layernorm<<<4096, 256, 0, stream>>>(x2f, ln2_g, ln2_b, lnb);

  k_gemm<128, 128, 2, 2, 2, false, false, true><<<dim3(32, 32), 256, 0, stream>>>(
      lnb, fc_wT, fc_b, nullptr, nullptr, fcb, 4096, 4096, 1024);

  k_gemm<128, 128, 2, 2, 0, true, true, true><<<dim3(32, 8), 256, 0, stream>>>(
      fcb, mlp_pwT, mlp_pb, x2f, x1f, x1b, 4096, 1024, 4096);

  k_gemm<64, 64, 2, 2, 1, false, false, true><<<dim3(64, 1), 256, 0, stream>>>(
      x1b, a2_dwT, a2_db, nullptr, nullptr, hb, 4096, 64, 1024);

  k_gemm<128, 128, 2, 2, 0, true, true, false><<<dim3(32, 8), 256, 0, stream>>>(
      hb, a2_uwT, a2_ub, x1f, (float*)d_out, nullptr, 4096, 1024, 64);
}

// Round 7
// 551.630 us; speedup vs baseline: 1.0144x; 1.0144x over previous
//
#include <hip/hip_runtime.h>
#include <hip/hip_bf16.h>
#include <cstdint>

#define DEVI __device__ __forceinline__

using bf16x8 = __attribute__((ext_vector_type(8))) short;
using f32x4  = __attribute__((ext_vector_type(4))) float;

DEVI short f2b(float f) {
  __hip_bfloat16 h = __float2bfloat16(f);
  return *reinterpret_cast<short*>(&h);
}
DEVI float b2f(short s) {
  __hip_bfloat16 h = *reinterpret_cast<__hip_bfloat16*>(&s);
  return __bfloat162float(h);
}
DEVI uint32_t pk2(float a, float b) {
  return (uint32_t)(uint16_t)f2b(a) | ((uint32_t)(uint16_t)f2b(b) << 16);
}

DEVI f32x4 mfma16(bf16x8 a, bf16x8 b, f32x4 c) {
  return __builtin_amdgcn_mfma_f32_16x16x32_bf16(a, b, c, 0, 0, 0);
}

DEVI void gload_lds16(const void* g, void* l) {
  __builtin_amdgcn_global_load_lds(
      (const __attribute__((address_space(1))) void*)g,
      (__attribute__((address_space(3))) void*)l, 16, 0, 0);
}

DEVI float gelu_f(float x) {
  float u = 1.5957691216057308f * (x + 0.044715f * x * x * x); // 2z
  float e = __expf(u);
  float t = 1.f - 2.f / (e + 1.f); // tanh(z)
  return 0.5f * x * (1.f + t);
}

// ---------------- weight transpose + fp32->bf16 convert ----------------
__global__ void k_wt(const float* __restrict__ in, short* __restrict__ out,
                     int R, int Cc) {
  __shared__ float tile[32][33];
  int c0 = blockIdx.x * 32;
  int r0 = blockIdx.y * 32;
  int tx = threadIdx.x, ty = threadIdx.y;
  for (int i = ty; i < 32; i += 8) {
    int r = r0 + i, c = c0 + tx;
    tile[i][tx] = (r < R && c < Cc) ? in[(size_t)r * Cc + c] : 0.f;
  }
  __syncthreads();
  for (int i = ty; i < 32; i += 8) {
    int orow = c0 + i;
    int ocol = r0 + tx;
    if (orow < Cc && ocol < R) out[(size_t)orow * R + ocol] = f2b(tile[tx][i]);
  }
}

// ---------------- layernorm: fp32 in -> bf16 out (C=1024) ----------------
__global__ void k_layernorm(const float* __restrict__ x, const float* __restrict__ g,
                            const float* __restrict__ bta, short* __restrict__ out) {
  const int C = 1024;
  int row = blockIdx.x;
  const float* xr = x + (size_t)row * C;
  f32x4 v = *(const f32x4*)(xr + threadIdx.x * 4);
  float s = v[0] + v[1] + v[2] + v[3];
  float s2 = v[0]*v[0] + v[1]*v[1] + v[2]*v[2] + v[3]*v[3];
#pragma unroll
  for (int m = 1; m < 64; m <<= 1) { s += __shfl_xor(s, m); s2 += __shfl_xor(s2, m); }
  __shared__ float red[8];
  int w = threadIdx.x >> 6;
  if ((threadIdx.x & 63) == 0) { red[w] = s; red[4 + w] = s2; }
  __syncthreads();
  s = red[0] + red[1] + red[2] + red[3];
  s2 = red[4] + red[5] + red[6] + red[7];
  float mu = s * (1.f / 1024.f);
  float rstd = rsqrtf(s2 * (1.f / 1024.f) - mu * mu + 1e-5f);
#pragma unroll
  for (int j = 0; j < 4; ++j) {
    int c = threadIdx.x * 4 + j;
    out[(size_t)row * C + c] = f2b((v[j] - mu) * rstd * g[c] + bta[c]);
  }
}

// ---------------- V transpose: qkv bf16 [4096][3072] -> vT [32][64][2048] ----------------
__global__ void k_vtrans(const short* __restrict__ qkv, short* __restrict__ vT) {
  __shared__ short tile[32][72];
  int b = blockIdx.z, h = blockIdx.y;
  int t0 = blockIdx.x * 32;
  int tx = threadIdx.x;
  int ty = threadIdx.y;
  const size_t inbase = ((size_t)(b * 2048 + t0)) * 3072 + 2048 + h * 64;
  for (int i = ty; i < 32; i += 8) {
    tile[i][tx]      = qkv[inbase + (size_t)i * 3072 + tx];
    tile[i][tx + 32] = qkv[inbase + (size_t)i * 3072 + tx + 32];
  }
  __syncthreads();
  const size_t outbase = ((size_t)(b * 16 + h) * 64) * 2048 + t0;
  for (int d = ty; d < 64; d += 8)
    vT[outbase + (size_t)d * 2048 + tx] = tile[tx][d];
}

// ---------------- GEMM ----------------
template <int BM, int BN, int WGM, int WGN, int ACT, bool RESID, bool OUTF, bool OUTB>
__global__ __launch_bounds__(256, 2) void k_gemm(
    const short* __restrict__ A, const short* __restrict__ BT,
    const float* __restrict__ bias, const float* __restrict__ resid,
    float* __restrict__ outf, short* __restrict__ outb,
    int M, int N, int K) {
  static_assert(WGM * WGN == 4, "4 waves");
  constexpr int TM = BM / WGM, TN = BN / WGN;
  constexpr int FM = TM / 16, FN = TN / 16;
  __shared__ short As[BM * 32];
  __shared__ short Bs[BN * 32];
  const int tid = threadIdx.x;
  const int wid = tid >> 6, l = tid & 63, lr = l & 15, lg = l >> 4;
  const int wm = wid / WGN, wn = wid % WGN;
  const int rowA0 = blockIdx.x * BM;
  const int colB0 = blockIdx.y * BN;

  f32x4 acc[FM][FN];
#pragma unroll
  for (int i = 0; i < FM; ++i)
#pragma unroll
    for (int j = 0; j < FN; ++j) acc[i][j] = f32x4{0.f, 0.f, 0.f, 0.f};

  for (int k0 = 0; k0 < K; k0 += 32) {
    __syncthreads();
#pragma unroll
    for (int it = 0; it < (BM * 64) / 4096; ++it) {
      int bo = it * 4096 + tid * 16;
      int row = bo >> 6, col = (bo & 63) >> 1;
      gload_lds16(A + (size_t)(rowA0 + row) * K + k0 + col, (void*)(As + (bo >> 1)));
    }
#pragma unroll
    for (int it = 0; it < (BN * 64) / 4096; ++it) {
      int bo = it * 4096 + tid * 16;
      int row = bo >> 6, col = (bo & 63) >> 1;
      gload_lds16(BT + (size_t)(colB0 + row) * K + k0 + col, (void*)(Bs + (bo >> 1)));
    }
    __syncthreads();
    bf16x8 af[FM], bfr[FN];
#pragma unroll
    for (int i = 0; i < FM; ++i)
      af[i] = *(const bf16x8*)(As + (wm * TM + i * 16 + lr) * 32 + lg * 8);
#pragma unroll
    for (int j = 0; j < FN; ++j)
      bfr[j] = *(const bf16x8*)(Bs + (wn * TN + j * 16 + lr) * 32 + lg * 8);
#pragma unroll
    for (int i = 0; i < FM; ++i)
#pragma unroll
      for (int j = 0; j < FN; ++j)
        acc[i][j] = mfma16(af[i], bfr[j], acc[i][j]);
  }

  const int row0 = rowA0 + wm * TM + lg * 4;
  const int col0 = colB0 + wn * TN + lr;
#pragma unroll
  for (int i = 0; i < FM; ++i) {
#pragma unroll
    for (int j = 0; j < FN; ++j) {
#pragma unroll
      for (int r = 0; r < 4; ++r) {
        int row = row0 + i * 16 + r;
        int col = col0 + j * 16;
        float v = acc[i][j][r] + bias[col];
        if (ACT == 1) v = fmaxf(v, 0.f);
        if (ACT == 2) v = gelu_f(v);
        size_t idx = (size_t)row * N + col;
        if (RESID) v += resid[idx];
        if (OUTF) outf[idx] = v;
        if (OUTB) outb[idx] = f2b(v);
      }
    }
  }
}

// ---------------- flash-style causal attention (swapped QK^T, pipelined) ----
// qkv bf16 [4096][3072]; vT bf16 [32][64][2048]; y bf16 [4096][1024]
// Wave = 16 q rows. S^T = mfma(K, Q): lane (lr,lg) reg r holds
// S[kv=lg*4+r (+16 tile1)][q=lr]. exp2-domain softmax, defer-max.
// P redistributed to PV B-operand layout IN REGISTERS via xor32/xor16
// shuffle exchange (no LDS). K prefetched one tile ahead; V issued at
// tile top -> both latencies hide under compute.
__global__ __launch_bounds__(256, 3) void k_attn(
    const short* __restrict__ qkv, const short* __restrict__ vT,
    short* __restrict__ y) {
  constexpr int T = 2048, C3 = 3072;
  const int tid = threadIdx.x;
  const int wid = tid >> 6, l = tid & 63, lr = l & 15, lg = l >> 4;
  const int bh = blockIdx.x, b = bh >> 4, h = bh & 15;
  const int qt = (int)(gridDim.y - 1 - blockIdx.y);  // longest-first
  const int q0 = qt * 64 + wid * 16;

  // Q fragment (B-operand layout): Q[q=lr][d=lg*8+j] * 0.125*log2(e)
  const float qscale = 0.125f * 1.4426950408889634f;
  const short* qptr = qkv + (size_t)(b * T + q0 + lr) * C3 + h * 64;
  bf16x8 qr0 = *(const bf16x8*)(qptr + lg * 8);
  bf16x8 qr1 = *(const bf16x8*)(qptr + 32 + lg * 8);
  bf16x8 qf0, qf1;
#pragma unroll
  for (int j = 0; j < 8; ++j) {
    qf0[j] = f2b(b2f(qr0[j]) * qscale);
    qf1[j] = f2b(b2f(qr1[j]) * qscale);
  }

  const short* kbase = qkv + (size_t)(b * T) * C3 + 1024 + h * 64;
  const short* vtb = vT + (size_t)bh * 64 * 2048;

  f32x4 o[4];
#pragma unroll
  for (int d = 0; d < 4; ++d) o[d] = f32x4{0.f, 0.f, 0.f, 0.f};
  float m = -1e30f, lsum = 0.f;

  // lane-constant predicates for the P exchange
  const bool lglt2 = (lg < 2);
  const bool lg0 = (lg == 0), lg1 = (lg == 1), lg2 = (lg == 2), lg3 = (lg == 3);
  const int q = q0 + lr;

  auto loadK = [&](bf16x8* kf, int kv0) {
    const short* kp = kbase + (size_t)(kv0 + lr) * C3;
    kf[0] = *(const bf16x8*)(kp + lg * 8);
    kf[1] = *(const bf16x8*)(kp + 32 + lg * 8);
    kf[2] = *(const bf16x8*)(kp + 16 * C3 + lg * 8);
    kf[3] = *(const bf16x8*)(kp + 16 * C3 + 32 + lg * 8);
  };

  auto tile = [&](bf16x8* kf, bf16x8* knext, int kv0, bool pre) {
    // issue V loads early (consumed after softmax)
    bf16x8 vf0 = *(const bf16x8*)(vtb + (size_t)(0 * 16 + lr) * 2048 + kv0 + lg * 8);
    bf16x8 vf1 = *(const bf16x8*)(vtb + (size_t)(1 * 16 + lr) * 2048 + kv0 + lg * 8);
    bf16x8 vf2 = *(const bf16x8*)(vtb + (size_t)(2 * 16 + lr) * 2048 + kv0 + lg * 8);
    bf16x8 vf3 = *(const bf16x8*)(vtb + (size_t)(3 * 16 + lr) * 2048 + kv0 + lg * 8);
    // prefetch next tile's K (used next iteration)
    if (pre) loadK(knext, kv0 + 32);

    f32x4 s0 = {0.f, 0.f, 0.f, 0.f}, s1 = {0.f, 0.f, 0.f, 0.f};
    s0 = mfma16(kf[0], qf0, s0);
    s0 = mfma16(kf[1], qf1, s0);
    s1 = mfma16(kf[2], qf0, s1);
    s1 = mfma16(kf[3], qf1, s1);

    // causal mask (always applied; no-op for interior tiles)
#pragma unroll
    for (int r = 0; r < 4; ++r) {
      if (kv0 + lg * 4 + r > q) s0[r] = -1e30f;
      if (kv0 + 16 + lg * 4 + r > q) s1[r] = -1e30f;
    }

    float mx = fmaxf(fmaxf(fmaxf(s0[0], s0[1]), fmaxf(s0[2], s0[3])),
                     fmaxf(fmaxf(s1[0], s1[1]), fmaxf(s1[2], s1[3])));
    mx = fmaxf(mx, __shfl_xor(mx, 16));
    mx = fmaxf(mx, __shfl_xor(mx, 32));
    if (__any(mx > m + 8.f)) {  // defer-max
      float mn = fmaxf(m, mx);
      float corr = exp2f(m - mn);
      m = mn;
      lsum *= corr;
#pragma unroll
      for (int d = 0; d < 4; ++d)
#pragma unroll
        for (int r = 0; r < 4; ++r) o[d][r] *= corr;
    }
    float p0 = exp2f(s0[0] - m), p1 = exp2f(s0[1] - m);
    float p2 = exp2f(s0[2] - m), p3 = exp2f(s0[3] - m);
    float p4 = exp2f(s1[0] - m), p5 = exp2f(s1[1] - m);
    float p6 = exp2f(s1[2] - m), p7 = exp2f(s1[3] - m);
    lsum += ((p0 + p1) + (p2 + p3)) + ((p4 + p5) + (p6 + p7));

    // pack: a = tile0 (kv = lg*4+0..3), b = tile1 (kv = 16+lg*4+0..3)
    uint32_t a0 = pk2(p0, p1), a1 = pk2(p2, p3);
    uint32_t b0 = pk2(p4, p5), b1 = pk2(p6, p7);
    // step A (xor 32): lg<2 sends b-pair, lg>=2 sends a-pair
    uint32_t ux = lglt2 ? b0 : a0;
    uint32_t uy = lglt2 ? b1 : a1;
    uint32_t rx0 = (uint32_t)__shfl_xor((int)ux, 32);
    uint32_t rx1 = (uint32_t)__shfl_xor((int)uy, 32);
    // step B (xor 16): lg0 sends rx(=a2), lg1 sends a(=a1), lg2 sends b(=b2), lg3 sends rx(=b1)
    uint32_t vx = lg1 ? a0 : (lg2 ? b0 : rx0);
    uint32_t vy = lg1 ? a1 : (lg2 ? b1 : rx1);
    uint32_t rv0 = (uint32_t)__shfl_xor((int)vx, 16);
    uint32_t rv1 = (uint32_t)__shfl_xor((int)vy, 16);
    // assemble PV B-fragment: pf[j] = P[q=lr][kv=lg*8+j]
    union {
      bf16x8 v;
      uint32_t u[4];
    } P;
    P.u[0] = lg0 ? a0 : (lg2 ? rx0 : rv0);
    P.u[1] = lg0 ? a1 : (lg2 ? rx1 : rv1);
    P.u[2] = lg3 ? b0 : (lg1 ? rx0 : rv0);
    P.u[3] = lg3 ? b1 : (lg1 ? rx1 : rv1);

    o[0] = mfma16(vf0, P.v, o[0]);
    o[1] = mfma16(vf1, P.v, o[1]);
    o[2] = mfma16(vf2, P.v, o[2]);
    o[3] = mfma16(vf3, P.v, o[3]);
  };

  bf16x8 KA[4], KB[4];
  loadK(KA, 0);
  const int n = (q0 >> 5) + 1;  // full tiles + diagonal tile
  int t = 0, kv0 = 0;
  while (true) {
    tile(KA, KB, kv0, t + 1 < n);
    ++t; kv0 += 32;
    if (t == n) break;
    tile(KB, KA, kv0, t + 1 < n);
    ++t; kv0 += 32;
    if (t == n) break;
  }

  lsum += __shfl_xor(lsum, 16);
  lsum += __shfl_xor(lsum, 32);
  float inv = 1.f / lsum;

  short* yp = y + (size_t)(b * T + q0 + lr) * 1024 + h * 64;
#pragma unroll
  for (int dt = 0; dt < 4; ++dt) {
    uint2 wv;
    wv.x = pk2(o[dt][0] * inv, o[dt][1] * inv);
    wv.y = pk2(o[dt][2] * inv, o[dt][3] * inv);
    *(uint2*)(yp + dt * 16 + lg * 4) = wv;
  }
}

extern "C" void kernel_launch(void* const* d_in, const int* in_sizes, int n_in,
                              void* d_out, int out_size, void* d_ws, size_t ws_size,
                              hipStream_t stream) {
  (void)in_sizes; (void)n_in; (void)out_size; (void)ws_size;
  const float* x0     = (const float*)d_in[0];
  const float* ln1_g  = (const float*)d_in[1];
  const float* ln1_b  = (const float*)d_in[2];
  const float* attn_w = (const float*)d_in[3];
  const float* attn_b = (const float*)d_in[4];
  const float* proj_w = (const float*)d_in[5];
  const float* proj_b = (const float*)d_in[6];
  const float* a1_dw  = (const float*)d_in[7];
  const float* a1_db  = (const float*)d_in[8];
  const float* a1_uw  = (const float*)d_in[9];
  const float* a1_ub  = (const float*)d_in[10];
  const float* ln2_g  = (const float*)d_in[11];
  const float* ln2_b  = (const float*)d_in[12];
  const float* fc_w   = (const float*)d_in[13];
  const float* fc_b   = (const float*)d_in[14];
  const float* mlp_pw = (const float*)d_in[15];
  const float* mlp_pb = (const float*)d_in[16];
  const float* a2_dw  = (const float*)d_in[17];
  const float* a2_db  = (const float*)d_in[18];
  const float* a2_uw  = (const float*)d_in[19];
  const float* a2_ub  = (const float*)d_in[20];

  char* ws = (char*)d_ws;
  size_t off = 0;
  auto alloc = [&](size_t bytes) {
    char* p = ws + off;
    off = (off + bytes + 255) & ~(size_t)255;
    return p;
  };

  short* attn_wT = (short*)alloc(3072ull * 1024 * 2);
  short* proj_wT = (short*)alloc(1024ull * 1024 * 2);
  short* fc_wT   = (short*)alloc(4096ull * 1024 * 2);
  short* mlp_pwT = (short*)alloc(1024ull * 4096 * 2);
  short* a1_dwT  = (short*)alloc(64ull * 1024 * 2);
  short* a1_uwT  = (short*)alloc(1024ull * 64 * 2);
  short* a2_dwT  = (short*)alloc(64ull * 1024 * 2);
  short* a2_uwT  = (short*)alloc(1024ull * 64 * 2);
  short* lnb     = (short*)alloc(4096ull * 1024 * 2);
  char*  big     = alloc(4096ull * 4096 * 2);
  short* qkvb    = (short*)big;
  short* vTb     = (short*)(big + 4096ull * 3072 * 2);
  short* fcb     = (short*)big;
  short* yb      = (short*)alloc(4096ull * 1024 * 2);
  float* x1f     = (float*)alloc(4096ull * 1024 * 4);
  float* x2f     = (float*)alloc(4096ull * 1024 * 4);
  short* x1b     = (short*)alloc(4096ull * 1024 * 2);
  short* hb      = (short*)alloc(4096ull * 64 * 2);

  dim3 tb(32, 8);
  k_wt<<<dim3(3072 / 32, 1024 / 32), tb, 0, stream>>>(attn_w, attn_wT, 1024, 3072);
  k_wt<<<dim3(1024 / 32, 1024 / 32), tb, 0, stream>>>(proj_w, proj_wT, 1024, 1024);
  k_wt<<<dim3(4096 / 32, 1024 / 32), tb, 0, stream>>>(fc_w, fc_wT, 1024, 4096);
  k_wt<<<dim3(1024 / 32, 4096 / 32), tb, 0, stream>>>(mlp_pw, mlp_pwT, 4096, 1024);
  k_wt<<<dim3(64 / 32, 1024 / 32), tb, 0, stream>>>(a1_dw, a1_dwT, 1024, 64);
  k_wt<<<dim3(1024 / 32, 64 / 32), tb, 0, stream>>>(a1_uw, a1_uwT, 64, 1024);
  k_wt<<<dim3(64 / 32, 1024 / 32), tb, 0, stream>>>(a2_dw, a2_dwT, 1024, 64);
  k_wt<<<dim3(1024 / 32, 64 / 32), tb, 0, stream>>>(a2_uw, a2_uwT, 64, 1024);

  k_layernorm<<<4096, 256, 0, stream>>>(x0, ln1_g, ln1_b, lnb);

  k_gemm<128, 128, 2, 2, 0, false, false, true><<<dim3(32, 24), 256, 0, stream>>>(
      lnb, attn_wT, attn_b, nullptr, nullptr, qkvb, 4096, 3072, 1024);

  k_vtrans<<<dim3(64, 16, 2), tb, 0, stream>>>(qkvb, vTb);

  k_attn<<<dim3(32, 32), 256, 0, stream>>>(qkvb, vTb, yb);

  k_gemm<128, 128, 2, 2, 0, true, true, true><<<dim3(32, 8), 256, 0, stream>>>(
      yb, proj_wT, proj_b, x0, x1f, x1b, 4096, 1024, 1024);

  k_gemm<64, 64, 2, 2, 1, false, false, true><<<dim3(64, 1), 256, 0, stream>>>(
      x1b, a1_dwT, a1_db, nullptr, nullptr, hb, 4096, 64, 1024);

  k_gemm<128, 128, 2, 2, 0, true, true, false><<<dim3(32, 8), 256, 0, stream>>>(
      hb, a1_uwT, a1_ub, x1f, x2f, nullptr, 4096, 1024, 64);

  k_layernorm<<<4096, 256, 0, stream>>>(x2f, ln2_g, ln2_b, lnb);

  k_gemm<128, 128, 2, 2, 2, false, false, true><<<dim3(32, 32), 256, 0, stream>>>(
      lnb, fc_wT, fc_b, nullptr, nullptr, fcb, 4096, 4096, 1024);

  k_gemm<128, 128, 2, 2, 0, true, true, true><<<dim3(32, 8), 256, 0, stream>>>(
      fcb, mlp_pwT, mlp_pb, x2f, x1f, x1b, 4096, 1024, 4096);

  k_gemm<64, 64, 2, 2, 1, false, false, true><<<dim3(64, 1), 256, 0, stream>>>(
      x1b, a2_dwT, a2_db, nullptr, nullptr, hb, 4096, 64, 1024);

  k_gemm<128, 128, 2, 2, 0, true, true, false><<<dim3(32, 8), 256, 0, stream>>>(
      hb, a2_uwT, a2_ub, x1f, (float*)d_out, nullptr, 4096, 1024, 64);
}

// Round 9
// 480.013 us; speedup vs baseline: 1.1658x; 1.1492x over previous
//
#include <hip/hip_runtime.h>
#include <hip/hip_bf16.h>
#include <cstdint>

#define DEVI __device__ __forceinline__

using bf16x8 = __attribute__((ext_vector_type(8))) short;
using f32x4  = __attribute__((ext_vector_type(4))) float;

DEVI short f2b(float f) {
  __hip_bfloat16 h = __float2bfloat16(f);
  return *reinterpret_cast<short*>(&h);
}
DEVI float b2f(short s) {
  __hip_bfloat16 h = *reinterpret_cast<__hip_bfloat16*>(&s);
  return __bfloat162float(h);
}
DEVI uint32_t pk2(float a, float b) {
  return (uint32_t)(uint16_t)f2b(a) | ((uint32_t)(uint16_t)f2b(b) << 16);
}

DEVI f32x4 mfma16(bf16x8 a, bf16x8 b, f32x4 c) {
  return __builtin_amdgcn_mfma_f32_16x16x32_bf16(a, b, c, 0, 0, 0);
}

DEVI void gload_lds16(const void* g, void* l) {
  __builtin_amdgcn_global_load_lds(
      (const __attribute__((address_space(1))) void*)g,
      (__attribute__((address_space(3))) void*)l, 16, 0, 0);
}

DEVI float gelu_f(float x) {
  float u = 1.5957691216057308f * (x + 0.044715f * x * x * x); // 2z
  float e = __expf(u);
  float t = 1.f - 2.f / (e + 1.f); // tanh(z)
  return 0.5f * x * (1.f + t);
}

// ---------------- weight transpose + fp32->bf16 convert ----------------
__global__ void k_wt(const float* __restrict__ in, short* __restrict__ out,
                     int R, int Cc) {
  __shared__ float tile[32][33];
  int c0 = blockIdx.x * 32;
  int r0 = blockIdx.y * 32;
  int tx = threadIdx.x, ty = threadIdx.y;
  for (int i = ty; i < 32; i += 8) {
    int r = r0 + i, c = c0 + tx;
    tile[i][tx] = (r < R && c < Cc) ? in[(size_t)r * Cc + c] : 0.f;
  }
  __syncthreads();
  for (int i = ty; i < 32; i += 8) {
    int orow = c0 + i;
    int ocol = r0 + tx;
    if (orow < Cc && ocol < R) out[(size_t)orow * R + ocol] = f2b(tile[tx][i]);
  }
}

// ---------------- layernorm: fp32 in -> bf16 out (C=1024) ----------------
__global__ void k_layernorm(const float* __restrict__ x, const float* __restrict__ g,
                            const float* __restrict__ bta, short* __restrict__ out) {
  const int C = 1024;
  int row = blockIdx.x;
  const float* xr = x + (size_t)row * C;
  f32x4 v = *(const f32x4*)(xr + threadIdx.x * 4);
  float s = v[0] + v[1] + v[2] + v[3];
  float s2 = v[0]*v[0] + v[1]*v[1] + v[2]*v[2] + v[3]*v[3];
#pragma unroll
  for (int m = 1; m < 64; m <<= 1) { s += __shfl_xor(s, m); s2 += __shfl_xor(s2, m); }
  __shared__ float red[8];
  int w = threadIdx.x >> 6;
  if ((threadIdx.x & 63) == 0) { red[w] = s; red[4 + w] = s2; }
  __syncthreads();
  s = red[0] + red[1] + red[2] + red[3];
  s2 = red[4] + red[5] + red[6] + red[7];
  float mu = s * (1.f / 1024.f);
  float rstd = rsqrtf(s2 * (1.f / 1024.f) - mu * mu + 1e-5f);
#pragma unroll
  for (int j = 0; j < 4; ++j) {
    int c = threadIdx.x * 4 + j;
    out[(size_t)row * C + c] = f2b((v[j] - mu) * rstd * g[c] + bta[c]);
  }
}

// ---------------- V transpose: qkv bf16 [4096][3072] -> vT [32][64][2048] ----------------
__global__ void k_vtrans(const short* __restrict__ qkv, short* __restrict__ vT) {
  __shared__ short tile[32][72];
  int b = blockIdx.z, h = blockIdx.y;
  int t0 = blockIdx.x * 32;
  int tx = threadIdx.x;
  int ty = threadIdx.y;
  const size_t inbase = ((size_t)(b * 2048 + t0)) * 3072 + 2048 + h * 64;
  for (int i = ty; i < 32; i += 8) {
    tile[i][tx]      = qkv[inbase + (size_t)i * 3072 + tx];
    tile[i][tx + 32] = qkv[inbase + (size_t)i * 3072 + tx + 32];
  }
  __syncthreads();
  const size_t outbase = ((size_t)(b * 16 + h) * 64) * 2048 + t0;
  for (int d = ty; d < 64; d += 8)
    vT[outbase + (size_t)d * 2048 + tx] = tile[tx][d];
}

// ---------------- GEMM ----------------
template <int BM, int BN, int WGM, int WGN, int ACT, bool RESID, bool OUTF, bool OUTB>
__global__ __launch_bounds__(256, 2) void k_gemm(
    const short* __restrict__ A, const short* __restrict__ BT,
    const float* __restrict__ bias, const float* __restrict__ resid,
    float* __restrict__ outf, short* __restrict__ outb,
    int M, int N, int K) {
  static_assert(WGM * WGN == 4, "4 waves");
  constexpr int TM = BM / WGM, TN = BN / WGN;
  constexpr int FM = TM / 16, FN = TN / 16;
  __shared__ short As[BM * 32];
  __shared__ short Bs[BN * 32];
  const int tid = threadIdx.x;
  const int wid = tid >> 6, l = tid & 63, lr = l & 15, lg = l >> 4;
  const int wm = wid / WGN, wn = wid % WGN;
  const int rowA0 = blockIdx.x * BM;
  const int colB0 = blockIdx.y * BN;

  f32x4 acc[FM][FN];
#pragma unroll
  for (int i = 0; i < FM; ++i)
#pragma unroll
    for (int j = 0; j < FN; ++j) acc[i][j] = f32x4{0.f, 0.f, 0.f, 0.f};

  for (int k0 = 0; k0 < K; k0 += 32) {
    __syncthreads();
#pragma unroll
    for (int it = 0; it < (BM * 64) / 4096; ++it) {
      int bo = it * 4096 + tid * 16;
      int row = bo >> 6, col = (bo & 63) >> 1;
      gload_lds16(A + (size_t)(rowA0 + row) * K + k0 + col, (void*)(As + (bo >> 1)));
    }
#pragma unroll
    for (int it = 0; it < (BN * 64) / 4096; ++it) {
      int bo = it * 4096 + tid * 16;
      int row = bo >> 6, col = (bo & 63) >> 1;
      gload_lds16(BT + (size_t)(colB0 + row) * K + k0 + col, (void*)(Bs + (bo >> 1)));
    }
    __syncthreads();
    bf16x8 af[FM], bfr[FN];
#pragma unroll
    for (int i = 0; i < FM; ++i)
      af[i] = *(const bf16x8*)(As + (wm * TM + i * 16 + lr) * 32 + lg * 8);
#pragma unroll
    for (int j = 0; j < FN; ++j)
      bfr[j] = *(const bf16x8*)(Bs + (wn * TN + j * 16 + lr) * 32 + lg * 8);
#pragma unroll
    for (int i = 0; i < FM; ++i)
#pragma unroll
      for (int j = 0; j < FN; ++j)
        acc[i][j] = mfma16(af[i], bfr[j], acc[i][j]);
  }

  const int row0 = rowA0 + wm * TM + lg * 4;
  const int col0 = colB0 + wn * TN + lr;
#pragma unroll
  for (int i = 0; i < FM; ++i) {
#pragma unroll
    for (int j = 0; j < FN; ++j) {
#pragma unroll
      for (int r = 0; r < 4; ++r) {
        int row = row0 + i * 16 + r;
        int col = col0 + j * 16;
        float v = acc[i][j][r] + bias[col];
        if (ACT == 1) v = fmaxf(v, 0.f);
        if (ACT == 2) v = gelu_f(v);
        size_t idx = (size_t)row * N + col;
        if (RESID) v += resid[idx];
        if (OUTF) outf[idx] = v;
        if (OUTB) outb[idx] = f2b(v);
      }
    }
  }
}

// ---------------- flash-style causal attention, 8-wave LDS-shared K/V ----
// Block = 512 thr = 8 waves, QBLK=128 (16 q-rows/wave). Per KVBLK=32 tile,
// K (32x64, 4KB) and V^T (64x32, 4KB) are staged ONCE into LDS via
// global_load_lds (inverse-swizzled source, linear dest) and consumed by
// all 8 waves with swizzled conflict-free ds_reads (rule 21 / T2).
// Double-buffered: STAGE(t+1) issues before compute(t); __syncthreads()
// drains vmcnt. Softmax/P-exchange/O identical to verified R7 code.
__global__ __launch_bounds__(512, 4) void k_attn(
    const short* __restrict__ qkv, const short* __restrict__ vT,
    short* __restrict__ y) {
  constexpr int T = 2048, C3 = 3072;
  const int tid = threadIdx.x;
  const int wid = tid >> 6, l = tid & 63, lr = l & 15, lg = l >> 4;
  const int bh = blockIdx.x, b = bh >> 4, h = bh & 15;
  const int qt = (int)(gridDim.y - 1 - blockIdx.y);  // longest-first
  const int q0 = qt * 128 + wid * 16;

  __shared__ short lds[2][4096];  // [buf]: K shorts 0..2047, V shorts 2048..4095

  // Q fragment (B-operand layout): Q[q=lr][d=lg*8+j] * 0.125*log2(e)
  const float qscale = 0.125f * 1.4426950408889634f;
  const short* qptr = qkv + (size_t)(b * T + q0 + lr) * C3 + h * 64;
  bf16x8 qr0 = *(const bf16x8*)(qptr + lg * 8);
  bf16x8 qr1 = *(const bf16x8*)(qptr + 32 + lg * 8);
  bf16x8 qf0, qf1;
#pragma unroll
  for (int j = 0; j < 8; ++j) {
    qf0[j] = f2b(b2f(qr0[j]) * qscale);
    qf1[j] = f2b(b2f(qr1[j]) * qscale);
  }

  const short* kbase = qkv + (size_t)(b * T) * C3 + 1024 + h * 64;
  const short* vtb = vT + (size_t)bh * 64 * 2048;

  // ---- staging setup: threads 0-255 stage K, 256-511 stage V ----
  // K linear o (bytes, 32 rows x 128B): swz = o ^ ((row&7)<<4), row=o>>7.
  // V linear o (bytes, 64 rows x 64B): swz = o ^ (((o>>7)&3)<<4), row=o>>6.
  // LDS[p] = G[s(p)] (involution) -> reads use swizzled addr, dest linear.
  const bool isK = (tid < 256);
  const int p = (isK ? tid : (tid - 256)) * 16;  // byte offset in region
  int sK_row = 0, sK_half = 0, sV_d = 0, sV_half = 0;
  {
    if (isK) {
      int s = p ^ (((p >> 7) & 7) << 4);
      sK_row = s >> 7; sK_half = (s & 127) >> 1;   // shorts within row
    } else {
      int s = p ^ (((p >> 7) & 3) << 4);
      sV_d = s >> 6; sV_half = (s & 63) >> 1;
    }
  }
  short* dst0 = &lds[0][(isK ? 0 : 2048) + (p >> 1)];
  short* dst1 = &lds[1][(isK ? 0 : 2048) + (p >> 1)];

  auto STAGE = [&](int buf, int kv0) {
    const short* g = isK
        ? kbase + (size_t)(kv0 + sK_row) * C3 + sK_half
        : vtb + (size_t)sV_d * T + kv0 + sV_half;
    gload_lds16(g, buf ? dst1 : dst0);
  };

  f32x4 o[4];
#pragma unroll
  for (int d = 0; d < 4; ++d) o[d] = f32x4{0.f, 0.f, 0.f, 0.f};
  float m = -1e30f, lsum = 0.f;

  const bool lglt2 = (lg < 2);
  const bool lg0 = (lg == 0), lg1 = (lg == 1), lg2 = (lg == 2), lg3 = (lg == 3);
  const int q = q0 + lr;
  const int xk = (lr & 7) << 4;                  // K read swizzle bits
  const int ck0 = (lg * 16) ^ xk;                // K col bytes, d-half 0
  const int ck1 = (64 + lg * 16) ^ xk;           // K col bytes, d-half 1

  auto compute = [&](int buf, int kv0) {
    const short* Kl = &lds[buf][0];
    const short* Vl = &lds[buf][2048];
    bf16x8 kf0 = *(const bf16x8*)(Kl + ((lr * 128 + ck0) >> 1));
    bf16x8 kf1 = *(const bf16x8*)(Kl + ((lr * 128 + ck1) >> 1));
    bf16x8 kf2 = *(const bf16x8*)(Kl + (((16 + lr) * 128 + ck0) >> 1));
    bf16x8 kf3 = *(const bf16x8*)(Kl + (((16 + lr) * 128 + ck1) >> 1));
    bf16x8 vf[4];
#pragma unroll
    for (int dt = 0; dt < 4; ++dt) {
      int row = dt * 16 + lr;
      int cv = (lg * 16) ^ (((row >> 1) & 3) << 4);
      vf[dt] = *(const bf16x8*)(Vl + ((row * 64 + cv) >> 1));
    }

    f32x4 s0 = {0.f, 0.f, 0.f, 0.f}, s1 = {0.f, 0.f, 0.f, 0.f};
    s0 = mfma16(kf0, qf0, s0);
    s0 = mfma16(kf1, qf1, s0);
    s1 = mfma16(kf2, qf0, s1);
    s1 = mfma16(kf3, qf1, s1);

#pragma unroll
    for (int r = 0; r < 4; ++r) {
      if (kv0 + lg * 4 + r > q) s0[r] = -1e30f;
      if (kv0 + 16 + lg * 4 + r > q) s1[r] = -1e30f;
    }

    float mx = fmaxf(fmaxf(fmaxf(s0[0], s0[1]), fmaxf(s0[2], s0[3])),
                     fmaxf(fmaxf(s1[0], s1[1]), fmaxf(s1[2], s1[3])));
    mx = fmaxf(mx, __shfl_xor(mx, 16));
    mx = fmaxf(mx, __shfl_xor(mx, 32));
    if (__any(mx > m + 8.f)) {  // defer-max
      float mn = fmaxf(m, mx);
      float corr = exp2f(m - mn);
      m = mn;
      lsum *= corr;
#pragma unroll
      for (int d = 0; d < 4; ++d)
#pragma unroll
        for (int r = 0; r < 4; ++r) o[d][r] *= corr;
    }
    float p0 = exp2f(s0[0] - m), p1 = exp2f(s0[1] - m);
    float p2 = exp2f(s0[2] - m), p3 = exp2f(s0[3] - m);
    float p4 = exp2f(s1[0] - m), p5 = exp2f(s1[1] - m);
    float p6 = exp2f(s1[2] - m), p7 = exp2f(s1[3] - m);
    lsum += ((p0 + p1) + (p2 + p3)) + ((p4 + p5) + (p6 + p7));

    uint32_t a0 = pk2(p0, p1), a1 = pk2(p2, p3);
    uint32_t b0 = pk2(p4, p5), b1 = pk2(p6, p7);
    uint32_t ux = lglt2 ? b0 : a0;
    uint32_t uy = lglt2 ? b1 : a1;
    uint32_t rx0 = (uint32_t)__shfl_xor((int)ux, 32);
    uint32_t rx1 = (uint32_t)__shfl_xor((int)uy, 32);
    uint32_t vx = lg1 ? a0 : (lg2 ? b0 : rx0);
    uint32_t vy = lg1 ? a1 : (lg2 ? b1 : rx1);
    uint32_t rv0 = (uint32_t)__shfl_xor((int)vx, 16);
    uint32_t rv1 = (uint32_t)__shfl_xor((int)vy, 16);
    union {
      bf16x8 v;
      uint32_t u[4];
    } P;
    P.u[0] = lg0 ? a0 : (lg2 ? rx0 : rv0);
    P.u[1] = lg0 ? a1 : (lg2 ? rx1 : rv1);
    P.u[2] = lg3 ? b0 : (lg1 ? rx0 : rv0);
    P.u[3] = lg3 ? b1 : (lg1 ? rx1 : rv1);

    o[0] = mfma16(vf[0], P.v, o[0]);
    o[1] = mfma16(vf[1], P.v, o[1]);
    o[2] = mfma16(vf[2], P.v, o[2]);
    o[3] = mfma16(vf[3], P.v, o[3]);
  };

  const int ntb = 4 * (qt + 1);   // staged tiles for this block
  const int myend = q0 + 15;      // last kv row this wave needs
  STAGE(0, 0);
  __syncthreads();
  int cur = 0, kv0 = 0;
  for (int t = 0; t < ntb; ++t, kv0 += 32) {
    if (t + 1 < ntb) STAGE(cur ^ 1, kv0 + 32);
    if (kv0 <= myend) compute(cur, kv0);
    __syncthreads();   // drains vmcnt (stage) + lgkmcnt (reads)
    cur ^= 1;
  }

  lsum += __shfl_xor(lsum, 16);
  lsum += __shfl_xor(lsum, 32);
  float inv = 1.f / lsum;

  short* yp = y + (size_t)(b * T + q0 + lr) * 1024 + h * 64;
#pragma unroll
  for (int dt = 0; dt < 4; ++dt) {
    uint2 wv;
    wv.x = pk2(o[dt][0] * inv, o[dt][1] * inv);
    wv.y = pk2(o[dt][2] * inv, o[dt][3] * inv);
    *(uint2*)(yp + dt * 16 + lg * 4) = wv;
  }
}

extern "C" void kernel_launch(void* const* d_in, const int* in_sizes, int n_in,
                              void* d_out, int out_size, void* d_ws, size_t ws_size,
                              hipStream_t stream) {
  (void)in_sizes; (void)n_in; (void)out_size; (void)ws_size;
  const float* x0     = (const float*)d_in[0];
  const float* ln1_g  = (const float*)d_in[1];
  const float* ln1_b  = (const float*)d_in[2];
  const float* attn_w = (const float*)d_in[3];
  const float* attn_b = (const float*)d_in[4];
  const float* proj_w = (const float*)d_in[5];
  const float* proj_b = (const float*)d_in[6];
  const float* a1_dw  = (const float*)d_in[7];
  const float* a1_db  = (const float*)d_in[8];
  const float* a1_uw  = (const float*)d_in[9];
  const float* a1_ub  = (const float*)d_in[10];
  const float* ln2_g  = (const float*)d_in[11];
  const float* ln2_b  = (const float*)d_in[12];
  const float* fc_w   = (const float*)d_in[13];
  const float* fc_b   = (const float*)d_in[14];
  const float* mlp_pw = (const float*)d_in[15];
  const float* mlp_pb = (const float*)d_in[16];
  const float* a2_dw  = (const float*)d_in[17];
  const float* a2_db  = (const float*)d_in[18];
  const float* a2_uw  = (const float*)d_in[19];
  const float* a2_ub  = (const float*)d_in[20];

  char* ws = (char*)d_ws;
  size_t off = 0;
  auto alloc = [&](size_t bytes) {
    char* p = ws + off;
    off = (off + bytes + 255) & ~(size_t)255;
    return p;
  };

  short* attn_wT = (short*)alloc(3072ull * 1024 * 2);
  short* proj_wT = (short*)alloc(1024ull * 1024 * 2);
  short* fc_wT   = (short*)alloc(4096ull * 1024 * 2);
  short* mlp_pwT = (short*)alloc(1024ull * 4096 * 2);
  short* a1_dwT  = (short*)alloc(64ull * 1024 * 2);
  short* a1_uwT  = (short*)alloc(1024ull * 64 * 2);
  short* a2_dwT  = (short*)alloc(64ull * 1024 * 2);
  short* a2_uwT  = (short*)alloc(1024ull * 64 * 2);
  short* lnb     = (short*)alloc(4096ull * 1024 * 2);
  char*  big     = alloc(4096ull * 4096 * 2);
  short* qkvb    = (short*)big;
  short* vTb     = (short*)(big + 4096ull * 3072 * 2);
  short* fcb     = (short*)big;
  short* yb      = (short*)alloc(4096ull * 1024 * 2);
  float* x1f     = (float*)alloc(4096ull * 1024 * 4);
  float* x2f     = (float*)alloc(4096ull * 1024 * 4);
  short* x1b     = (short*)alloc(4096ull * 1024 * 2);
  short* hb      = (short*)alloc(4096ull * 64 * 2);

  dim3 tb(32, 8);
  k_wt<<<dim3(3072 / 32, 1024 / 32), tb, 0, stream>>>(attn_w, attn_wT, 1024, 3072);
  k_wt<<<dim3(1024 / 32, 1024 / 32), tb, 0, stream>>>(proj_w, proj_wT, 1024, 1024);
  k_wt<<<dim3(4096 / 32, 1024 / 32), tb, 0, stream>>>(fc_w, fc_wT, 1024, 4096);
  k_wt<<<dim3(1024 / 32, 4096 / 32), tb, 0, stream>>>(mlp_pw, mlp_pwT, 4096, 1024);
  k_wt<<<dim3(64 / 32, 1024 / 32), tb, 0, stream>>>(a1_dw, a1_dwT, 1024, 64);
  k_wt<<<dim3(1024 / 32, 64 / 32), tb, 0, stream>>>(a1_uw, a1_uwT, 64, 1024);
  k_wt<<<dim3(64 / 32, 1024 / 32), tb, 0, stream>>>(a2_dw, a2_dwT, 1024, 64);
  k_wt<<<dim3(1024 / 32, 64 / 32), tb, 0, stream>>>(a2_uw, a2_uwT, 64, 1024);

  k_layernorm<<<4096, 256, 0, stream>>>(x0, ln1_g, ln1_b, lnb);

  k_gemm<128, 128, 2, 2, 0, false, false, true><<<dim3(32, 24), 256, 0, stream>>>(
      lnb, attn_wT, attn_b, nullptr, nullptr, qkvb, 4096, 3072, 1024);

  k_vtrans<<<dim3(64, 16, 2), tb, 0, stream>>>(qkvb, vTb);

  k_attn<<<dim3(32, 16), 512, 0, stream>>>(qkvb, vTb, yb);

  k_gemm<128, 128, 2, 2, 0, true, true, true><<<dim3(32, 8), 256, 0, stream>>>(
      yb, proj_wT, proj_b, x0, x1f, x1b, 4096, 1024, 1024);

  k_gemm<64, 64, 2, 2, 1, false, false, true><<<dim3(64, 1), 256, 0, stream>>>(
      x1b, a1_dwT, a1_db, nullptr, nullptr, hb, 4096, 64, 1024);

  k_gemm<128, 128, 2, 2, 0, true, true, false><<<dim3(32, 8), 256, 0, stream>>>(
      hb, a1_uwT, a1_ub, x1f, x2f, nullptr, 4096, 1024, 64);

  k_layernorm<<<4096, 256, 0, stream>>>(x2f, ln2_g, ln2_b, lnb);

  k_gemm<128, 128, 2, 2, 2, false, false, true><<<dim3(32, 32), 256, 0, stream>>>(
      lnb, fc_wT, fc_b, nullptr, nullptr, fcb, 4096, 4096, 1024);

  k_gemm<128, 128, 2, 2, 0, true, true, true><<<dim3(32, 8), 256, 0, stream>>>(
      fcb, mlp_pwT, mlp_pb, x2f, x1f, x1b, 4096, 1024, 4096);

  k_gemm<64, 64, 2, 2, 1, false, false, true><<<dim3(64, 1), 256, 0, stream>>>(
      x1b, a2_dwT, a2_db, nullptr, nullptr, hb, 4096, 64, 1024);

  k_gemm<128, 128, 2, 2, 0, true, true, false><<<dim3(32, 8), 256, 0, stream>>>(
      hb, a2_uwT, a2_ub, x1f, (float*)d_out, nullptr, 4096, 1024, 64);
}